// Round 19
// baseline (14480.196 us; speedup 1.0000x reference)
//
#include <hip/hip_runtime.h>
#include <math.h>

#define BATCH 16
#define T 512
#define NT 6
#define START 4
#define STOP 5
#define NEGV -10000.0f
#define LOG2E 1.4426950408889634f
#define NBLK 16       // group size; role k owns units [16k,16k+16), all 4 gates
#define SPIN_LIM 131072u  // hang-safety only (~15ms); normal waits are ~1-2us

typedef __attribute__((ext_vector_type(8))) short short8;
typedef __attribute__((ext_vector_type(4))) float f32x4;
typedef __attribute__((ext_vector_type(4))) unsigned int u32x4;

__device__ __forceinline__ float fast_sig(float x) {
    float e = __builtin_amdgcn_exp2f(-LOG2E * x);
    return __builtin_amdgcn_rcpf(1.f + e);
}
__device__ __forceinline__ float fast_tanh(float x) {
    float e = __builtin_amdgcn_exp2f(-2.f * LOG2E * x);
    return (1.f - e) * __builtin_amdgcn_rcpf(1.f + e);
}
__device__ __forceinline__ unsigned bf16_rne(float f) {
    unsigned u = __builtin_bit_cast(unsigned, f);
    u += 0x7FFFu + ((u >> 16) & 1u);
    return u >> 16;
}
__device__ __forceinline__ float bf_lo(unsigned v) {
    return __builtin_bit_cast(float, (v & 0xffffu) << 16);
}
__device__ __forceinline__ float bf_hi(unsigned v) {
    return __builtin_bit_cast(float, v & 0xffff0000u);
}
// L1-bypassing (sc0) protocol accesses: deterministic same-XCD L2 coherence.
// "=&v" early-clobber: output must NOT alias the address register pair (r17 fault).
__device__ __forceinline__ int ld_flag_sc0(const int* p) {
    int v;
    asm volatile("global_load_dword %0, %1, off sc0\n\ts_waitcnt vmcnt(0)"
                 : "=&v"(v) : "v"(p) : "memory");
    return v;
}
__device__ __forceinline__ void st_u32_sc0(unsigned* p, unsigned v) {
    asm volatile("global_store_dword %0, %1, off sc0" :: "v"(p), "v"(v) : "memory");
}
__device__ __forceinline__ void st_u16_sc0(unsigned short* p, unsigned v) {
    asm volatile("global_store_short %0, %1, off sc0" :: "v"(p), "v"(v) : "memory");
}

// ws layout (byte offsets) — NO aliasing:
//   [0, 16MB)        Xpb bf16 [t][k][n][lane][j] (32KB/step page)
//   [16MB, 17MB)     WihT fp32 (dead after input_proj)
//   [17MB, 17.5MB)   Wf bf16 MFMA B-fragments
//   [17.5MB, +192K)  feats fp32 [b][t][6]
//   [18MB, 22MB)     Hg ushort [t][ks][b][ul]: sc0-written by XCD0's group; doubles as
//                    the exchange fabric (full history -> no page rotation, no dup store)
//   [24117248, +8KB) flags int[16][16] (64B stride; only group 0)
//   [24125440, +512B) tickets (tickets[0] = XCD0 election counter)
//   flags+tickets (2176 ints contiguous) zeroed by transpose_wih EVERY call.

__global__ void transpose_wih(const float* __restrict__ W_ih, float* __restrict__ WihT,
                              int* __restrict__ zero_region) {
    int o = blockIdx.x * blockDim.x + threadIdx.x;
    if (o < 2176) zero_region[o] = 0;   // flags + tickets
    if (o >= 256 * 1024) return;
    int k = o >> 10;
    int g = o & 1023;
    WihT[o] = W_ih[g * 256 + k];
}

// Pack W_hh (fp32 [1024][256]) into bf16 MFMA B-fragments (r6 layout, proven).
__global__ void wf_prep(const float* __restrict__ W_hh, unsigned short* __restrict__ Wf) {
    int t = blockIdx.x * 256 + threadIdx.x;  // 0..32767
    int l = t & 63, kt = (t >> 6) & 7, n = (t >> 9) & 3, w = t >> 11;
    int g = n * 256 + w * 16 + (l & 15);
    int kk = kt * 32 + (l >> 4) * 8;
    const float* src = W_hh + g * 256 + kk;
    unsigned short* dst = Wf + (size_t)t * 8;
#pragma unroll
    for (int j = 0; j < 8; j++) dst[j] = (unsigned short)bf16_rne(src[j]);
}

// One block = 16 (b,t) rows, 1024 threads = 1 per gate. Writes Xpb (bf16) in MFMA C-layout.
__global__ __launch_bounds__(1024) void input_proj(const int* __restrict__ sentence,
                                                   const float* __restrict__ embedding,
                                                   const float* __restrict__ WihT,
                                                   const float* __restrict__ b_ih,
                                                   const float* __restrict__ b_hh,
                                                   unsigned short* __restrict__ Xpb) {
    __shared__ __align__(16) float emb[16][260];
    int tid = threadIdx.x;
    int bt0 = blockIdx.x * 16;
    {
        int r = tid >> 6, j = tid & 63;
        int row = sentence[bt0 + r];
        const float4* src = (const float4*)(embedding + (size_t)row * 256);
        float4 v = src[j];
        float* dst = &emb[r][j * 4];
        dst[0] = v.x; dst[1] = v.y; dst[2] = v.z; dst[3] = v.w;
    }
    __syncthreads();
    int g = tid;
    float bias = b_ih[g] + b_hh[g];
    float acc[16];
#pragma unroll
    for (int r = 0; r < 16; r++) acc[r] = bias;
    const float* wp = WihT + g;
    for (int k4 = 0; k4 < 64; k4++) {
        float w0 = wp[(k4 * 4 + 0) * 1024];
        float w1 = wp[(k4 * 4 + 1) * 1024];
        float w2 = wp[(k4 * 4 + 2) * 1024];
        float w3 = wp[(k4 * 4 + 3) * 1024];
#pragma unroll
        for (int r = 0; r < 16; r++) {
            float4 e = *(const float4*)&emb[r][k4 * 4];
            acc[r] += w0 * e.x + w1 * e.y + w2 * e.z + w3 * e.w;
        }
    }
    int b = bt0 >> 9, t0 = bt0 & 511;
    int q = b >> 2, j = b & 3;
    int n = g >> 8, u = g & 255, k = u >> 4, cc = u & 15;
    int lane = q * 16 + cc;
#pragma unroll
    for (int r = 0; r < 16; r++) {
        int t = t0 + r;
        Xpb[(size_t)(((t * 16 + k) * 4 + n) * 64 + lane) * 4 + j] =
            (unsigned short)bf16_rne(acc[r]);
    }
}

// 384 blocks x 64 threads (ONE wave). Only XCD0 blocks elect (16 roles); everyone else
// exits. Role k computes ALL 4 gate tiles for units [16k,16k+16) -> i/f/g/o of each
// (batch,unit) land in the SAME lane -> lane-local c/h update: ZERO barriers, ZERO LDS.
// Step = poll(sc0) -> gather(sc0) -> 32 MFMA -> act -> publish(sc0 u16) -> vmcnt drain
// -> flag(sc0). Hg pages are both exchange fabric and full h history.
__global__ __launch_bounds__(64) void lstm_mfma(const unsigned short* __restrict__ Wf,
                                                const unsigned short* __restrict__ Xpb,
                                                unsigned short* __restrict__ Hg,
                                                int* __restrict__ flags,
                                                int* __restrict__ tickets) {
    int l = threadIdx.x;
    unsigned xcd_raw;
    asm volatile("s_getreg_b32 %0, hwreg(HW_REG_XCC_ID)" : "=s"(xcd_raw));
    if ((xcd_raw & 7) != 0) return;  // XCD0-only: its L2 is the exchange fabric
    int role = 0;
    if (l == 0)
        role = __hip_atomic_fetch_add(tickets, 1, __ATOMIC_RELAXED, __HIP_MEMORY_SCOPE_AGENT);
    role = __shfl(role, 0);
    if (role >= NBLK) return;
    int k = role;
    int q = l >> 4, c = l & 15;

    // all 4 gate-tile B-fragment sets: 32 x short8 = 128 VGPR (static subscripts; r9-proven)
    short8 wr[4][8];
#pragma unroll
    for (int n = 0; n < 4; n++)
#pragma unroll
        for (int kt = 0; kt < 8; kt++)
            wr[n][kt] = *(const short8*)(Wf + ((size_t)((k * 4 + n) * 8 + kt) * 64 + l) * 8);

    // Xp bf16 [t][k][n][lane][j]: per gate n this lane's 4 vals = 8B; t-stride 16384 ushorts
    const unsigned short* xb = Xpb + ((size_t)k * 4) * 256 + (size_t)l * 4;
    uint2 xv[4];
#pragma unroll
    for (int n = 0; n < 4; n++) xv[n] = *(const uint2*)(xb + n * 256);

    float c_st[4] = {0.f, 0.f, 0.f, 0.f};

    // gather base (ushort): A-frag row b=l&15, u-block (q>>1) + kt*2, ul half (q&1)*8
    int abase_us = (q >> 1) * 256 + (l & 15) * 16 + (q & 1) * 8;
    const int* pollp = flags + (l & 15) * 16;  // 4 lanes per producer flag
    unsigned* myflag = (unsigned*)(flags + k * 16);

    for (int t = 0; t < T; t++) {
        uint2 xn[4];
        if (t + 1 < T) {
            const unsigned short* xb1 = xb + (size_t)(t + 1) * 16384;
#pragma unroll
            for (int n = 0; n < 4; n++) xn[n] = *(const uint2*)(xb1 + n * 256);
        } else {
#pragma unroll
            for (int n = 0; n < 4; n++) xn[n] = xv[n];
        }

        f32x4 acc[4];
#pragma unroll
        for (int n = 0; n < 4; n++) {
            acc[n][0] = bf_lo(xv[n].x);
            acc[n][1] = bf_hi(xv[n].x);
            acc[n][2] = bf_lo(xv[n].y);
            acc[n][3] = bf_hi(xv[n].y);
        }

        if (t > 0) {
            // poll all 16 producer flags (sc0, self-throttled by load latency)
            unsigned spins = 0;
            bool dead = false;
            while (true) {
                int f = ld_flag_sc0(pollp);
                if (__all(f >= t)) break;
                if (++spins > SPIN_LIM) { dead = true; break; }
            }
            if (__any(dead)) return;  // hang-safety (should never fire with full group)
            __builtin_amdgcn_sched_barrier(0);

            // gather h(t-1): 8 x 16B sc0 loads, ONE vmcnt wait ("=&v": r17 lesson)
            const char* hb = (const char*)(Hg + (size_t)(t - 1) * 4096 + abase_us);
            const char* hb1 = hb + 4096;
            u32x4 r0, r1, r2, r3, r4, r5, r6, r7;
            asm volatile(
                "global_load_dwordx4 %0, %8, off sc0\n\t"
                "global_load_dwordx4 %1, %8, off offset:1024 sc0\n\t"
                "global_load_dwordx4 %2, %8, off offset:2048 sc0\n\t"
                "global_load_dwordx4 %3, %8, off offset:3072 sc0\n\t"
                "global_load_dwordx4 %4, %9, off sc0\n\t"
                "global_load_dwordx4 %5, %9, off offset:1024 sc0\n\t"
                "global_load_dwordx4 %6, %9, off offset:2048 sc0\n\t"
                "global_load_dwordx4 %7, %9, off offset:3072 sc0\n\t"
                "s_waitcnt vmcnt(0)"
                : "=&v"(r0), "=&v"(r1), "=&v"(r2), "=&v"(r3),
                  "=&v"(r4), "=&v"(r5), "=&v"(r6), "=&v"(r7)
                : "v"(hb), "v"(hb1) : "memory");
            short8 af[8];
            af[0] = __builtin_bit_cast(short8, r0);
            af[1] = __builtin_bit_cast(short8, r1);
            af[2] = __builtin_bit_cast(short8, r2);
            af[3] = __builtin_bit_cast(short8, r3);
            af[4] = __builtin_bit_cast(short8, r4);
            af[5] = __builtin_bit_cast(short8, r5);
            af[6] = __builtin_bit_cast(short8, r6);
            af[7] = __builtin_bit_cast(short8, r7);
            // 32 MFMAs: 4 independent dep-chains (one per gate) interleave on the pipe
#pragma unroll
            for (int kt = 0; kt < 8; kt++)
#pragma unroll
                for (int n = 0; n < 4; n++)
                    acc[n] = __builtin_amdgcn_mfma_f32_16x16x32_bf16(af[kt], wr[n][kt],
                                                                     acc[n], 0, 0, 0);
        }

        // lane-local act: lane (q,c) owns (b=q*4+j, u=k*16+c); publish straight to Hg page
        unsigned short* pg = Hg + (size_t)t * 4096 + k * 256 + c;
#pragma unroll
        for (int j = 0; j < 4; j++) {
            float iv = fast_sig(acc[0][j]);
            float fg = fast_sig(acc[1][j]);
            float gv = fast_tanh(acc[2][j]);
            float ov = fast_sig(acc[3][j]);
            c_st[j] = fg * c_st[j] + iv * gv;
            unsigned hv = bf16_rne(ov * fast_tanh(c_st[j]));
            st_u16_sc0(pg + (q * 4 + j) * 16, hv);
        }
        asm volatile("s_waitcnt vmcnt(0)" ::: "memory");  // h stores in L2 before the flag
        if (l == 0) st_u32_sc0(myflag, (unsigned)(t + 1));
#pragma unroll
        for (int n = 0; n < 4; n++) xv[n] = xn[n];
    }
}

// feats[b][t][tag] = h(b,t) . W_out[tag] + b_out[tag].  2048 blocks x 256, wave = one (b,t).
__global__ __launch_bounds__(256) void feats_k(const unsigned short* __restrict__ Hg,
                                               const float* __restrict__ W_out,
                                               const float* __restrict__ b_out,
                                               float* __restrict__ feats) {
    int wid = blockIdx.x * 4 + (threadIdx.x >> 6);
    int l = threadIdx.x & 63;
    int b = wid >> 9, t = wid & 511;
    uint2 hv = *(const uint2*)(Hg + (size_t)t * 4096 + (l >> 2) * 256 + b * 16 + (l & 3) * 4);
    float h0 = bf_lo(hv.x), h1 = bf_hi(hv.x), h2 = bf_lo(hv.y), h3 = bf_hi(hv.y);
    int ub = (l >> 2) * 16 + (l & 3) * 4;
#pragma unroll
    for (int tag = 0; tag < 6; tag++) {
        float4 w = *(const float4*)(W_out + tag * 256 + ub);
        float p = h0 * w.x + h1 * w.y + h2 * w.z + h3 * w.w;
#pragma unroll
        for (int off = 32; off; off >>= 1) p += __shfl_down(p, off);
        if (l == 0) feats[((size_t)b * 512 + t) * 6 + tag] = p + b_out[tag];
    }
}

// 16 blocks x 64 threads. Lane nx owns next-tag nx; fv broadcast via shfl each step.
__global__ __launch_bounds__(64) void crf_scan(const float* __restrict__ feats,
                                               const float* __restrict__ trans,
                                               float* __restrict__ out) {
    __shared__ float fl[T * 6];
    __shared__ unsigned char bp[T * 8];
    int b = blockIdx.x, tid = threadIdx.x;
    const float4* src = (const float4*)(feats + (size_t)b * 3072);
#pragma unroll
    for (int i = 0; i < 12; i++) ((float4*)fl)[tid + i * 64] = src[tid + i * 64];
    int nx = (tid < 6) ? tid : 0;
    float tr0 = trans[nx * 6 + 0], tr1 = trans[nx * 6 + 1], tr2 = trans[nx * 6 + 2],
          tr3 = trans[nx * 6 + 3], tr4 = trans[nx * 6 + 4], tr5 = trans[nx * 6 + 5];
    float fv0 = NEGV, fv1 = NEGV, fv2 = NEGV, fv3 = NEGV, fv4 = 0.f, fv5 = NEGV;  // START=4
    __syncthreads();
    for (int t = 0; t < T; t++) {
        float best = fv0 + tr0; int arg = 0; float s;
        s = fv1 + tr1; if (s > best) { best = s; arg = 1; }
        s = fv2 + tr2; if (s > best) { best = s; arg = 2; }
        s = fv3 + tr3; if (s > best) { best = s; arg = 3; }
        s = fv4 + tr4; if (s > best) { best = s; arg = 4; }
        s = fv5 + tr5; if (s > best) { best = s; arg = 5; }  // strict >: first-max
        float nf = best + fl[t * 6 + nx];
        if (tid < 6) bp[t * 8 + tid] = (unsigned char)arg;
        fv0 = __shfl(nf, 0); fv1 = __shfl(nf, 1); fv2 = __shfl(nf, 2);
        fv3 = __shfl(nf, 3); fv4 = __shfl(nf, 4); fv5 = __shfl(nf, 5);
    }
    __syncthreads();
    if (tid == 0) {
        float best = fv0 + trans[STOP * 6 + 0]; int arg = 0; float s;
        s = fv1 + trans[STOP * 6 + 1]; if (s > best) { best = s; arg = 1; }
        s = fv2 + trans[STOP * 6 + 2]; if (s > best) { best = s; arg = 2; }
        s = fv3 + trans[STOP * 6 + 3]; if (s > best) { best = s; arg = 3; }
        s = fv4 + trans[STOP * 6 + 4]; if (s > best) { best = s; arg = 4; }
        s = fv5 + trans[STOP * 6 + 5]; if (s > best) { best = s; arg = 5; }
        out[b] = best;
        int tag = arg;
        float* paths = out + 16 + (size_t)b * 512;
        for (int t = T - 1; t >= 0; t--) {
            paths[t] = (float)tag;
            tag = bp[t * 8 + tag];
        }
    }
}

extern "C" void kernel_launch(void* const* d_in, const int* in_sizes, int n_in,
                              void* d_out, int out_size, void* d_ws, size_t ws_size,
                              hipStream_t stream) {
    const int* sentence = (const int*)d_in[0];
    const float* embedding = (const float*)d_in[1];
    const float* W_ih = (const float*)d_in[2];
    const float* W_hh = (const float*)d_in[3];
    const float* b_ih = (const float*)d_in[4];
    const float* b_hh = (const float*)d_in[5];
    const float* W_out = (const float*)d_in[6];
    const float* b_out = (const float*)d_in[7];
    const float* trans = (const float*)d_in[8];
    float* out = (float*)d_out;
    char* ws = (char*)d_ws;

    unsigned short* Xpb = (unsigned short*)ws;                 // 16 MB
    float* WihT = (float*)(ws + 16777216);                     // 1 MB
    unsigned short* Wf = (unsigned short*)(ws + 17825792);     // 512 KB
    float* feats = (float*)(ws + 18350080);                    // 192 KB
    unsigned short* Hg = (unsigned short*)(ws + 18874368);     // 4 MB history+exchange
    int* flags = (int*)(ws + 24117248);                        // 8 KB (group 0 only)
    int* tickets = (int*)(ws + 24125440);                      // 512 B

    hipLaunchKernelGGL(transpose_wih, dim3(1024), dim3(256), 0, stream, W_ih, WihT, flags);
    hipLaunchKernelGGL(input_proj, dim3(BATCH * T / 16), dim3(1024), 0, stream,
                       sentence, embedding, WihT, b_ih, b_hh, Xpb);
    hipLaunchKernelGGL(wf_prep, dim3(128), dim3(256), 0, stream, W_hh, Wf);
    hipLaunchKernelGGL(lstm_mfma, dim3(384), dim3(64), 0, stream, Wf, Xpb, Hg,
                       flags, tickets);
    hipLaunchKernelGGL(feats_k, dim3(2048), dim3(256), 0, stream, Hg, W_out, b_out, feats);
    hipLaunchKernelGGL(crf_scan, dim3(BATCH), dim3(64), 0, stream, feats, trans, out);
}

// Round 20
// 635.833 us; speedup vs baseline: 22.7736x; 22.7736x over previous
//
#include <hip/hip_runtime.h>
#include <math.h>

#define BATCH 16
#define T 512
#define NT 6
#define START 4
#define STOP 5
#define NEGV -10000.0f
#define LOG2E 1.4426950408889634f
#define NBLK 16    // participants per XCD group; role k owns gate cols {n*256+k*16+c}
#define NPAGE 16   // exchange pages per group
#define SPIN_LIM 4096u

typedef __attribute__((ext_vector_type(8))) short short8;
typedef __attribute__((ext_vector_type(4))) float f32x4;
typedef __attribute__((ext_vector_type(4))) unsigned int u32x4;

__device__ __forceinline__ float fast_sig(float x) {
    float e = __builtin_amdgcn_exp2f(-LOG2E * x);
    return __builtin_amdgcn_rcpf(1.f + e);
}
__device__ __forceinline__ float fast_tanh(float x) {
    float e = __builtin_amdgcn_exp2f(-2.f * LOG2E * x);
    return (1.f - e) * __builtin_amdgcn_rcpf(1.f + e);
}
__device__ __forceinline__ unsigned bf16_rne(float f) {
    unsigned u = __builtin_bit_cast(unsigned, f);
    u += 0x7FFFu + ((u >> 16) & 1u);
    return u >> 16;
}
__device__ __forceinline__ float bf_lo(unsigned v) {
    return __builtin_bit_cast(float, (v & 0xffffu) << 16);
}
__device__ __forceinline__ float bf_hi(unsigned v) {
    return __builtin_bit_cast(float, v & 0xffff0000u);
}
// L1-bypassing (sc0) protocol accesses: always see / write the XCD's L2 directly.
// NOTE "=&v" early-clobber: output must NOT alias the address register pair (r17 fault).
__device__ __forceinline__ int ld_flag_sc0(const int* p) {
    int v;
    asm volatile("global_load_dword %0, %1, off sc0\n\ts_waitcnt vmcnt(0)"
                 : "=&v"(v) : "v"(p) : "memory");
    return v;
}
__device__ __forceinline__ void st_u32_sc0(unsigned* p, unsigned v) {
    asm volatile("global_store_dword %0, %1, off sc0" :: "v"(p), "v"(v) : "memory");
}

// ws layout (byte offsets) — NO aliasing:
//   [0, 16MB)        Xpb bf16 [t][k][n][lane][j] (32KB/step page)
//   [16MB, 17MB)     WihT fp32 (dead after input_proj)
//   [17MB, 17.5MB)   Wf bf16 MFMA B-fragments
//   [17.5MB, +192K)  feats fp32 [b][t][6]
//   [18MB, 22MB)     Hg ushort [t][ks][b][ul] h history (8KB/step page)
//   [22MB, 23MB)     Ex u64 [xcd][page=16][1024]: per-XCD exchange pages (L2-local, sc0)
//   [24117248, +8KB) flags int[8 groups][16 blocks][16] (64B stride)
//   [24125440, +512B) tickets int[8][16] (per-XCD election counters)
//   flags+tickets (2176 ints contiguous) zeroed by prep EVERY call.

// Fused prep: WihT transpose + flags/tickets zero (blocks 0..1023) AND W_hh bf16
// MFMA-fragment pack (blocks 1024..1151). Saves one kernel launch vs r18.
__global__ void prep(const float* __restrict__ W_ih, float* __restrict__ WihT,
                     int* __restrict__ zero_region,
                     const float* __restrict__ W_hh, unsigned short* __restrict__ Wf) {
    if (blockIdx.x < 1024) {
        int o = blockIdx.x * blockDim.x + threadIdx.x;
        if (o < 2176) zero_region[o] = 0;   // flags (2048) + tickets (128)
        int k = o >> 10;
        int g = o & 1023;
        WihT[o] = W_ih[g * 256 + k];
    } else {
        int t = (blockIdx.x - 1024) * 256 + threadIdx.x;  // 0..32767
        int l = t & 63, kt = (t >> 6) & 7, n = (t >> 9) & 3, w = t >> 11;
        int g = n * 256 + w * 16 + (l & 15);
        int kk = kt * 32 + (l >> 4) * 8;
        const float* src = W_hh + g * 256 + kk;
        unsigned short* dst = Wf + (size_t)t * 8;
#pragma unroll
        for (int j = 0; j < 8; j++) dst[j] = (unsigned short)bf16_rne(src[j]);
    }
}

// One block = 16 (b,t) rows, 1024 threads = 1 per gate. Writes Xpb (bf16) in MFMA C-layout.
__global__ __launch_bounds__(1024) void input_proj(const int* __restrict__ sentence,
                                                   const float* __restrict__ embedding,
                                                   const float* __restrict__ WihT,
                                                   const float* __restrict__ b_ih,
                                                   const float* __restrict__ b_hh,
                                                   unsigned short* __restrict__ Xpb) {
    __shared__ __align__(16) float emb[16][260];
    int tid = threadIdx.x;
    int bt0 = blockIdx.x * 16;
    {
        int r = tid >> 6, j = tid & 63;
        int row = sentence[bt0 + r];
        const float4* src = (const float4*)(embedding + (size_t)row * 256);
        float4 v = src[j];
        float* dst = &emb[r][j * 4];
        dst[0] = v.x; dst[1] = v.y; dst[2] = v.z; dst[3] = v.w;
    }
    __syncthreads();
    int g = tid;
    float bias = b_ih[g] + b_hh[g];
    float acc[16];
#pragma unroll
    for (int r = 0; r < 16; r++) acc[r] = bias;
    const float* wp = WihT + g;
    for (int k4 = 0; k4 < 64; k4++) {
        float w0 = wp[(k4 * 4 + 0) * 1024];
        float w1 = wp[(k4 * 4 + 1) * 1024];
        float w2 = wp[(k4 * 4 + 2) * 1024];
        float w3 = wp[(k4 * 4 + 3) * 1024];
#pragma unroll
        for (int r = 0; r < 16; r++) {
            float4 e = *(const float4*)&emb[r][k4 * 4];
            acc[r] += w0 * e.x + w1 * e.y + w2 * e.z + w3 * e.w;
        }
    }
    int b = bt0 >> 9, t0 = bt0 & 511;
    int q = b >> 2, j = b & 3;
    int n = g >> 8, u = g & 255, k = u >> 4, cc = u & 15;
    int lane = q * 16 + cc;
#pragma unroll
    for (int r = 0; r < 16; r++) {
        int t = t0 + r;
        Xpb[(size_t)(((t * 16 + k) * 4 + n) * 64 + lane) * 4 + j] =
            (unsigned short)bf16_rne(acc[r]);
    }
}

// 384 blocks x 256 threads — r18's PROVEN kernel (lstm 449us), byte-identical.
// Blocks elect into per-XCD groups of 16 (device-scope ticket); role>=16 exits;
// under-populated groups time out (~0.7ms) and exit. All protocol traffic is XCD-LOCAL
// via sc0 (L1-bypass) loads/stores -> deterministic same-L2 coherence. All live groups
// compute identical bytes redundantly; >=1 full group exists by pigeonhole.
__global__ __launch_bounds__(256) void lstm_mfma(const unsigned short* __restrict__ Wf,
                                                 const unsigned short* __restrict__ Xpb,
                                                 unsigned short* __restrict__ Hg,
                                                 unsigned long long* __restrict__ Ex,
                                                 int* __restrict__ flags,
                                                 int* __restrict__ tickets) {
    __shared__ float gl[4][16][16];
    __shared__ int sh_role;
    __shared__ int go_s, abort_s;
    int tid = threadIdx.x;

    unsigned xcd_raw;
    asm volatile("s_getreg_b32 %0, hwreg(HW_REG_XCC_ID)" : "=s"(xcd_raw));
    int xcd = (int)(xcd_raw & 7);
    if (tid == 0) {
        sh_role = __hip_atomic_fetch_add(&tickets[xcd * 16], 1, __ATOMIC_RELAXED,
                                         __HIP_MEMORY_SCOPE_AGENT);
        go_s = 0;
        abort_s = 0;
    }
    __syncthreads();
    int role = sh_role;
    if (role >= NBLK) return;  // uniform whole-block exit
    int k = role;

    int n = tid >> 6;          // wave = gate type (i,f,g,o)
    int l = tid & 63;
    int q = l >> 4;

    // B-fragments of this role's W_hh slice: 8 x short8 = 32 VGPR (r6 verbatim)
    short8 wr[8];
#pragma unroll
    for (int kt = 0; kt < 8; kt++)
        wr[kt] = *(const short8*)(Wf + ((size_t)((k * 4 + n) * 8 + kt) * 64 + l) * 8);

    const unsigned short* xb = Xpb + ((size_t)(k * 4 + n)) * 256 + (size_t)l * 4;
    uint2 xv = *(const uint2*)xb;

    // A-frag base within an exchange page (ull units) — r6/r15 verbatim
    int abase_us = (q >> 1) * 256 + (l & 15) * 16 + (q & 1) * 8;
    int abase_ull = abase_us >> 2;

    float c_st = 0.f;
    int b_own = tid >> 4, ul = tid & 15;

    unsigned long long* ExG = Ex + (size_t)xcd * NPAGE * 1024;
    int* flagsG = flags + xcd * 256;
    const int* pollp = flagsG + (l & 15) * 16;  // 4 lanes per flag; covers all 16 producers
    unsigned* myflag = (unsigned*)(flagsG + k * 16);

    for (int t = 0; t < T; t++) {
        uint2 xn = xv;
        if (t + 1 < T) xn = *(const uint2*)(xb + (size_t)(t + 1) * 16384);

        f32x4 acc;
        acc[0] = bf_lo(xv.x); acc[1] = bf_hi(xv.x);
        acc[2] = bf_lo(xv.y); acc[3] = bf_hi(xv.y);

        if (t > 0) {
            if (tid < 64) {  // wave 0: poll L2 flags via sc0; then raise the LDS gate
                unsigned spins = 0;
                bool dead = false;
                while (true) {
                    int f = ld_flag_sc0(pollp);
                    if (__all(f >= t)) break;
                    if (++spins > SPIN_LIM) { dead = true; break; }
                    asm volatile("s_sleep 1");
                }
                if (l == 0) {
                    if (dead) {
                        *((volatile int*)&abort_s) = 1;
                        *((volatile int*)&go_s) = 0x7fffffff;
                    } else {
                        *((volatile int*)&go_s) = t;
                    }
                }
            } else {  // waves 1-3: gate on LDS (no L2 traffic)
                while (*((volatile int*)&go_s) < t) { asm volatile("s_sleep 1"); }
            }
            if (*((volatile int*)&abort_s)) return;  // dead group: all waves exit
            asm volatile("" ::: "memory");
            __builtin_amdgcn_sched_barrier(0);

            // gather h(t-1) from the XCD-local page: 8 x 16B sc0 loads, ONE vmcnt wait.
            // "=&v" early-clobber: outputs must not alias the address pairs (r17 fault).
            const char* hb =
                (const char*)(ExG + (size_t)((t - 1) & (NPAGE - 1)) * 1024 + abase_ull);
            const char* hb1 = hb + 4096;
            u32x4 r0, r1, r2, r3, r4, r5, r6, r7;
            asm volatile(
                "global_load_dwordx4 %0, %8, off sc0\n\t"
                "global_load_dwordx4 %1, %8, off offset:1024 sc0\n\t"
                "global_load_dwordx4 %2, %8, off offset:2048 sc0\n\t"
                "global_load_dwordx4 %3, %8, off offset:3072 sc0\n\t"
                "global_load_dwordx4 %4, %9, off sc0\n\t"
                "global_load_dwordx4 %5, %9, off offset:1024 sc0\n\t"
                "global_load_dwordx4 %6, %9, off offset:2048 sc0\n\t"
                "global_load_dwordx4 %7, %9, off offset:3072 sc0\n\t"
                "s_waitcnt vmcnt(0)"
                : "=&v"(r0), "=&v"(r1), "=&v"(r2), "=&v"(r3),
                  "=&v"(r4), "=&v"(r5), "=&v"(r6), "=&v"(r7)
                : "v"(hb), "v"(hb1) : "memory");
            short8 af0 = __builtin_bit_cast(short8, r0);
            short8 af1 = __builtin_bit_cast(short8, r1);
            short8 af2 = __builtin_bit_cast(short8, r2);
            short8 af3 = __builtin_bit_cast(short8, r3);
            short8 af4 = __builtin_bit_cast(short8, r4);
            short8 af5 = __builtin_bit_cast(short8, r5);
            short8 af6 = __builtin_bit_cast(short8, r6);
            short8 af7 = __builtin_bit_cast(short8, r7);
            acc = __builtin_amdgcn_mfma_f32_16x16x32_bf16(af0, wr[0], acc, 0, 0, 0);
            acc = __builtin_amdgcn_mfma_f32_16x16x32_bf16(af1, wr[1], acc, 0, 0, 0);
            acc = __builtin_amdgcn_mfma_f32_16x16x32_bf16(af2, wr[2], acc, 0, 0, 0);
            acc = __builtin_amdgcn_mfma_f32_16x16x32_bf16(af3, wr[3], acc, 0, 0, 0);
            acc = __builtin_amdgcn_mfma_f32_16x16x32_bf16(af4, wr[4], acc, 0, 0, 0);
            acc = __builtin_amdgcn_mfma_f32_16x16x32_bf16(af5, wr[5], acc, 0, 0, 0);
            acc = __builtin_amdgcn_mfma_f32_16x16x32_bf16(af6, wr[6], acc, 0, 0, 0);
            acc = __builtin_amdgcn_mfma_f32_16x16x32_bf16(af7, wr[7], acc, 0, 0, 0);
        }

        // gate exchange: lane (q,c) reg j -> (b=q*4+j, col c), gate n
        {
            int c = l & 15;
#pragma unroll
            for (int j = 0; j < 4; j++) gl[n][q * 4 + j][c] = acc[j];
        }
        __syncthreads();  // A: gates ready

        // act: all 256 threads, 1 (b,u) each; pair via shfl; even-ul threads publish u32
        {
            float iv = fast_sig(gl[0][b_own][ul]);
            float fg = fast_sig(gl[1][b_own][ul]);
            float gv = fast_tanh(gl[2][b_own][ul]);
            float ov = fast_sig(gl[3][b_own][ul]);
            c_st = fg * c_st + iv * gv;
            unsigned hv = bf16_rne(ov * fast_tanh(c_st));
            unsigned part = (unsigned)__shfl_xor((int)hv, 1);
            if ((ul & 1) == 0) {
                unsigned word = hv | (part << 16);
                int widx = k * 128 + b_own * 8 + (ul >> 1);
                // XCD-local exchange page: sc0 store -> straight into this XCD's L2
                st_u32_sc0((unsigned*)(ExG + (size_t)(t & (NPAGE - 1)) * 1024) + widx, word);
                // global h history for feats_k (plain store; kernel-boundary coherence)
                ((unsigned*)(Hg + (size_t)t * 4096 + k * 256))[b_own * 8 + (ul >> 1)] = word;
            }
        }
        __syncthreads();  // B: per-wave vmcnt drain -> all h stores in L2 before the flag
        if (tid == 0) st_u32_sc0(myflag, (unsigned)(t + 1));
        xv = xn;
    }
}

// feats[b][t][tag] = h(b,t) . W_out[tag] + b_out[tag].  2048 blocks x 256, wave = one (b,t).
__global__ __launch_bounds__(256) void feats_k(const unsigned short* __restrict__ Hg,
                                               const float* __restrict__ W_out,
                                               const float* __restrict__ b_out,
                                               float* __restrict__ feats) {
    int wid = blockIdx.x * 4 + (threadIdx.x >> 6);
    int l = threadIdx.x & 63;
    int b = wid >> 9, t = wid & 511;
    uint2 hv = *(const uint2*)(Hg + (size_t)t * 4096 + (l >> 2) * 256 + b * 16 + (l & 3) * 4);
    float h0 = bf_lo(hv.x), h1 = bf_hi(hv.x), h2 = bf_lo(hv.y), h3 = bf_hi(hv.y);
    int ub = (l >> 2) * 16 + (l & 3) * 4;
#pragma unroll
    for (int tag = 0; tag < 6; tag++) {
        float4 w = *(const float4*)(W_out + tag * 256 + ub);
        float p = h0 * w.x + h1 * w.y + h2 * w.z + h3 * w.w;
#pragma unroll
        for (int off = 32; off; off >>= 1) p += __shfl_down(p, off);
        if (l == 0) feats[((size_t)b * 512 + t) * 6 + tag] = p + b_out[tag];
    }
}

// 16 blocks x 64 threads. Lane nx owns next-tag nx; fv broadcast via shfl each step.
__global__ __launch_bounds__(64) void crf_scan(const float* __restrict__ feats,
                                               const float* __restrict__ trans,
                                               float* __restrict__ out) {
    __shared__ float fl[T * 6];
    __shared__ unsigned char bp[T * 8];
    int b = blockIdx.x, tid = threadIdx.x;
    const float4* src = (const float4*)(feats + (size_t)b * 3072);
#pragma unroll
    for (int i = 0; i < 12; i++) ((float4*)fl)[tid + i * 64] = src[tid + i * 64];
    int nx = (tid < 6) ? tid : 0;
    float tr0 = trans[nx * 6 + 0], tr1 = trans[nx * 6 + 1], tr2 = trans[nx * 6 + 2],
          tr3 = trans[nx * 6 + 3], tr4 = trans[nx * 6 + 4], tr5 = trans[nx * 6 + 5];
    float fv0 = NEGV, fv1 = NEGV, fv2 = NEGV, fv3 = NEGV, fv4 = 0.f, fv5 = NEGV;  // START=4
    __syncthreads();
    for (int t = 0; t < T; t++) {
        float best = fv0 + tr0; int arg = 0; float s;
        s = fv1 + tr1; if (s > best) { best = s; arg = 1; }
        s = fv2 + tr2; if (s > best) { best = s; arg = 2; }
        s = fv3 + tr3; if (s > best) { best = s; arg = 3; }
        s = fv4 + tr4; if (s > best) { best = s; arg = 4; }
        s = fv5 + tr5; if (s > best) { best = s; arg = 5; }  // strict >: first-max
        float nf = best + fl[t * 6 + nx];
        if (tid < 6) bp[t * 8 + tid] = (unsigned char)arg;
        fv0 = __shfl(nf, 0); fv1 = __shfl(nf, 1); fv2 = __shfl(nf, 2);
        fv3 = __shfl(nf, 3); fv4 = __shfl(nf, 4); fv5 = __shfl(nf, 5);
    }
    __syncthreads();
    if (tid == 0) {
        float best = fv0 + trans[STOP * 6 + 0]; int arg = 0; float s;
        s = fv1 + trans[STOP * 6 + 1]; if (s > best) { best = s; arg = 1; }
        s = fv2 + trans[STOP * 6 + 2]; if (s > best) { best = s; arg = 2; }
        s = fv3 + trans[STOP * 6 + 3]; if (s > best) { best = s; arg = 3; }
        s = fv4 + trans[STOP * 6 + 4]; if (s > best) { best = s; arg = 4; }
        s = fv5 + trans[STOP * 6 + 5]; if (s > best) { best = s; arg = 5; }
        out[b] = best;
        int tag = arg;
        float* paths = out + 16 + (size_t)b * 512;
        for (int t = T - 1; t >= 0; t--) {
            paths[t] = (float)tag;
            tag = bp[t * 8 + tag];
        }
    }
}

extern "C" void kernel_launch(void* const* d_in, const int* in_sizes, int n_in,
                              void* d_out, int out_size, void* d_ws, size_t ws_size,
                              hipStream_t stream) {
    const int* sentence = (const int*)d_in[0];
    const float* embedding = (const float*)d_in[1];
    const float* W_ih = (const float*)d_in[2];
    const float* W_hh = (const float*)d_in[3];
    const float* b_ih = (const float*)d_in[4];
    const float* b_hh = (const float*)d_in[5];
    const float* W_out = (const float*)d_in[6];
    const float* b_out = (const float*)d_in[7];
    const float* trans = (const float*)d_in[8];
    float* out = (float*)d_out;
    char* ws = (char*)d_ws;

    unsigned short* Xpb = (unsigned short*)ws;                 // 16 MB
    float* WihT = (float*)(ws + 16777216);                     // 1 MB
    unsigned short* Wf = (unsigned short*)(ws + 17825792);     // 512 KB
    float* feats = (float*)(ws + 18350080);                    // 192 KB
    unsigned short* Hg = (unsigned short*)(ws + 18874368);     // 4 MB history
    unsigned long long* Ex = (unsigned long long*)(ws + 23068672);  // 1 MB exchange
    int* flags = (int*)(ws + 24117248);                        // 8 KB
    int* tickets = (int*)(ws + 24125440);                      // 512 B

    hipLaunchKernelGGL(prep, dim3(1152), dim3(256), 0, stream, W_ih, WihT, flags, W_hh, Wf);
    hipLaunchKernelGGL(input_proj, dim3(BATCH * T / 16), dim3(1024), 0, stream,
                       sentence, embedding, WihT, b_ih, b_hh, Xpb);
    hipLaunchKernelGGL(lstm_mfma, dim3(384), dim3(256), 0, stream, Wf, Xpb, Hg, Ex,
                       flags, tickets);
    hipLaunchKernelGGL(feats_k, dim3(2048), dim3(256), 0, stream, Hg, W_out, b_out, feats);
    hipLaunchKernelGGL(crf_scan, dim3(BATCH), dim3(64), 0, stream, feats, trans, out);
}